// Round 1
// baseline (4732.255 us; speedup 1.0000x reference)
//
#include <hip/hip_runtime.h>
#include <hip/hip_bf16.h>

// GRU forward, T=512 B=256 I=H=256 fp32 in, fp32 [B,1] out.
// Design:
//  - Phase 1 (gi_gemm): gi[t,b,g] = x @ W_ih^T as bf16 into d_ws. MFMA 16x16x32,
//    weights preloaded into registers, A-tile staged in swizzled LDS.
//  - Phase 2 (gru_step): persistent recurrent kernel, 16 blocks x 1024 thr
//    (B_sub=16 batch rows per block = MFMA M). W_hh fragments live in VGPRs for
//    all 512 steps. h fp32 in registers; bf16 copy in double-buffered swizzled
//    LDS for A-fragments. One __syncthreads per step.
//  - Host picks chunked two-phase if ws_size allows, else fused fallback
//    (gi computed by MFMA in the recurrent kernel; ~2x slower, no ws needed).
// MFMA layout: relies only on D[m=(l>>4)*4+q][n=l&15] (m89-verified),
// A m=l&15 / B n=l&15; k-order within lane-group is consistent between A and B
// fragments, so the true hw k-permutation cancels in A*B.

#define TT 512
#define BB 256
#define II 256
#define HH 256
#define G3 768

typedef __attribute__((ext_vector_type(8))) short short8;
typedef __attribute__((ext_vector_type(4))) float f32x4;

__device__ __forceinline__ unsigned short rne_bf16(float f) {
  union { float f; unsigned u; } v; v.f = f;
  unsigned r = v.u + 0x7FFFu + ((v.u >> 16) & 1u);
  return (unsigned short)(r >> 16);
}
__device__ __forceinline__ float bf2f(unsigned short b) {
  union { unsigned u; float f; } v; v.u = ((unsigned)b) << 16;
  return v.f;
}
__device__ __forceinline__ float sigm(float x) { return 1.0f / (1.0f + __expf(-x)); }
__device__ __forceinline__ float tanhfast(float x) {
  return 1.0f - 2.0f / (__expf(2.0f * x) + 1.0f);
}

// 8 contiguous fp32 -> bf16 fragment (16B-aligned source)
__device__ __forceinline__ short8 ldw8(const float* __restrict__ p) {
  float4 a = *reinterpret_cast<const float4*>(p);
  float4 b = *reinterpret_cast<const float4*>(p + 4);
  short8 r;
  r[0] = (short)rne_bf16(a.x); r[1] = (short)rne_bf16(a.y);
  r[2] = (short)rne_bf16(a.z); r[3] = (short)rne_bf16(a.w);
  r[4] = (short)rne_bf16(b.x); r[5] = (short)rne_bf16(b.y);
  r[6] = (short)rne_bf16(b.z); r[7] = (short)rne_bf16(b.w);
  return r;
}

// swizzled [16][256] ushort LDS tile: element index for (row m, col k).
// XOR by m*16 (granularity 16 elems = 32B) keeps 16B reads aligned and spreads
// the 16 rows' same-column reads across banks (2-way aliasing only).
#define SWZ(m, k) ((m) * 256 + ((k) ^ ((m) * 16)))

// cooperative stage: 16 rows x 256 fp32 (row stride 256) -> swizzled bf16 LDS.
// requires 1024 threads.
__device__ __forceinline__ void stage16(unsigned short* lds,
                                        const float* __restrict__ src, int tid) {
  int m = tid >> 6, k0 = (tid & 63) << 2;
  float4 v = *reinterpret_cast<const float4*>(src + m * 256 + k0);
  ushort4 b;
  b.x = rne_bf16(v.x); b.y = rne_bf16(v.y);
  b.z = rne_bf16(v.z); b.w = rne_bf16(v.w);
  *reinterpret_cast<ushort4*>(lds + SWZ(m, k0)) = b;
}

// A fragment for chunk c from swizzled LDS tile: lane holds row m=l&15,
// k = c*32 + (l>>4)*8 + e  (same virtual k map as ldw8-built B fragments)
__device__ __forceinline__ short8 lda(const unsigned short* lds, int lane, int c) {
  int m = lane & 15;
  int k0 = c * 32 + (lane >> 4) * 8;
  return *reinterpret_cast<const short8*>(lds + SWZ(m, k0));
}

__device__ __forceinline__ f32x4 mfma16(short8 a, short8 b, f32x4 c) {
  return __builtin_amdgcn_mfma_f32_16x16x32_bf16(a, b, c, 0, 0, 0);
}

// ---------------- Phase 1: gi = x @ W_ih^T  (bf16 out) ----------------
__global__ __launch_bounds__(1024, 2) void gi_gemm(
    const float* __restrict__ x, const float* __restrict__ Wih,
    unsigned short* __restrict__ gi, int ntiles) {
  __shared__ unsigned short axl[16 * 256];
  int tid = threadIdx.x, lane = tid & 63, w = tid >> 6;
  int i15 = lane & 15, g4 = lane >> 4;
  int nb = 16 * w + i15;  // output column within each gate block
  short8 wf0[8], wf1[8], wf2[8];
#pragma unroll
  for (int c = 0; c < 8; ++c) {
    int ko = c * 32 + g4 * 8;
    wf0[c] = ldw8(Wih + (size_t)(0 * 256 + nb) * 256 + ko);
    wf1[c] = ldw8(Wih + (size_t)(1 * 256 + nb) * 256 + ko);
    wf2[c] = ldw8(Wih + (size_t)(2 * 256 + nb) * 256 + ko);
  }
  for (int tile = blockIdx.x; tile < ntiles; tile += gridDim.x) {
    stage16(axl, x + (size_t)tile * (16 * 256), tid);
    __syncthreads();
    short8 a[8];
#pragma unroll
    for (int c = 0; c < 8; ++c) a[c] = lda(axl, lane, c);
    f32x4 r = {0, 0, 0, 0}, z = {0, 0, 0, 0}, n = {0, 0, 0, 0};
#pragma unroll
    for (int c = 0; c < 8; ++c) {
      r = mfma16(a[c], wf0[c], r);
      z = mfma16(a[c], wf1[c], z);
      n = mfma16(a[c], wf2[c], n);
    }
    size_t rowb = (size_t)tile * 16 + (size_t)(g4 * 4);
#pragma unroll
    for (int q = 0; q < 4; ++q) {
      gi[(rowb + q) * G3 + 0 * 256 + nb] = rne_bf16(r[q]);
      gi[(rowb + q) * G3 + 1 * 256 + nb] = rne_bf16(z[q]);
      gi[(rowb + q) * G3 + 2 * 256 + nb] = rne_bf16(n[q]);
    }
    __syncthreads();  // WAR: frag reads done before next stage overwrites axl
  }
}

// ---------------- Phase 2: persistent GRU recurrence ----------------
template <bool FUSED>
__global__ __launch_bounds__(1024, 1) void gru_step(
    const float* __restrict__ x, const float* __restrict__ Wih,
    const float* __restrict__ Whh, const float* __restrict__ bih,
    const float* __restrict__ bhh, const float* __restrict__ Wout,
    const float* __restrict__ bout, const unsigned short* __restrict__ gi,
    float* __restrict__ hchk, float* __restrict__ out, int t0, int nt) {
  __shared__ unsigned short hbuf[2][16 * 256];
  __shared__ unsigned short xbuf[2][16 * 256];
  __shared__ float hfin[16][256];
  int tid = threadIdx.x, lane = tid & 63, w = tid >> 6;
  int i15 = lane & 15, g4 = lane >> 4;
  int b0 = blockIdx.x * 16;
  int j = 16 * w + i15;  // owned hidden-unit column

  // W_hh fragments, resident in VGPRs for the whole sequence
  short8 whh0[8], whh1[8], whh2[8];
#pragma unroll
  for (int c = 0; c < 8; ++c) {
    int ko = c * 32 + g4 * 8;
    whh0[c] = ldw8(Whh + (size_t)(0 * 256 + j) * 256 + ko);
    whh1[c] = ldw8(Whh + (size_t)(1 * 256 + j) * 256 + ko);
    whh2[c] = ldw8(Whh + (size_t)(2 * 256 + j) * 256 + ko);
  }
  short8 wih0[8], wih1[8], wih2[8];
  if constexpr (FUSED) {
#pragma unroll
    for (int c = 0; c < 8; ++c) {
      int ko = c * 32 + g4 * 8;
      wih0[c] = ldw8(Wih + (size_t)(0 * 256 + j) * 256 + ko);
      wih1[c] = ldw8(Wih + (size_t)(1 * 256 + j) * 256 + ko);
      wih2[c] = ldw8(Wih + (size_t)(2 * 256 + j) * 256 + ko);
    }
  }
  float bias_r = bih[j] + bhh[j];
  float bias_z = bih[256 + j] + bhh[256 + j];
  float bihn = bih[512 + j], bhhn = bhh[512 + j];

  f32x4 h = {0, 0, 0, 0};
  if (t0 == 0) {
    for (int idx = tid; idx < 16 * 256; idx += 1024) hbuf[0][idx] = 0;
  } else {
#pragma unroll
    for (int q = 0; q < 4; ++q) {
      int m = g4 * 4 + q;
      float hv = hchk[(size_t)(b0 + m) * 256 + j];
      h[q] = hv;
      hbuf[0][SWZ(m, j)] = rne_bf16(hv);
    }
  }
  if constexpr (FUSED) stage16(xbuf[0], x + ((size_t)t0 * BB + b0) * II, tid);
  __syncthreads();

  int goff[12];
  if constexpr (!FUSED) {
#pragma unroll
    for (int g = 0; g < 3; ++g)
#pragma unroll
      for (int q = 0; q < 4; ++q)
        goff[g * 4 + q] = (b0 + g4 * 4 + q) * G3 + g * 256 + j;
  }

  for (int lt = 0; lt < nt; ++lt) {
    int cur = lt & 1, nxt = cur ^ 1;
    float gir[4], giz[4], gin[4];
    if constexpr (!FUSED) {
      size_t base = (size_t)lt * (256 * G3);
#pragma unroll
      for (int q = 0; q < 4; ++q) {
        gir[q] = bf2f(gi[base + goff[q]]);
        giz[q] = bf2f(gi[base + goff[4 + q]]);
        gin[q] = bf2f(gi[base + goff[8 + q]]);
      }
    }
    short8 ah[8];
#pragma unroll
    for (int c = 0; c < 8; ++c) ah[c] = lda(hbuf[cur], lane, c);
    f32x4 ar = {0, 0, 0, 0}, az = {0, 0, 0, 0}, an = {0, 0, 0, 0};
    if constexpr (FUSED) {
      short8 axf[8];
#pragma unroll
      for (int c = 0; c < 8; ++c) axf[c] = lda(xbuf[cur], lane, c);
      f32x4 gr = {0, 0, 0, 0}, gz = {0, 0, 0, 0}, gn = {0, 0, 0, 0};
#pragma unroll
      for (int c = 0; c < 8; ++c) {
        gr = mfma16(axf[c], wih0[c], gr);
        gz = mfma16(axf[c], wih1[c], gz);
        gn = mfma16(axf[c], wih2[c], gn);
      }
#pragma unroll
      for (int q = 0; q < 4; ++q) { gir[q] = gr[q]; giz[q] = gz[q]; gin[q] = gn[q]; }
      if (lt + 1 < nt)  // prefetch next x tile into the other buffer
        stage16(xbuf[nxt], x + ((size_t)(t0 + lt + 1) * BB + b0) * II, tid);
    }
#pragma unroll
    for (int c = 0; c < 8; ++c) {
      ar = mfma16(ah[c], whh0[c], ar);
      az = mfma16(ah[c], whh1[c], az);
      an = mfma16(ah[c], whh2[c], an);
    }
#pragma unroll
    for (int q = 0; q < 4; ++q) {
      float r = sigm(ar[q] + gir[q] + bias_r);
      float zz = sigm(az[q] + giz[q] + bias_z);
      float nn = tanhfast(gin[q] + bihn + r * (an[q] + bhhn));
      float hq = (1.0f - zz) * nn + zz * h[q];
      h[q] = hq;
      int m = g4 * 4 + q;
      hbuf[nxt][SWZ(m, j)] = rne_bf16(hq);
    }
    __syncthreads();  // h(t+1) visible; all reads of hbuf[cur]/xbuf[cur] done
  }

  if (t0 + nt < TT) {
#pragma unroll
    for (int q = 0; q < 4; ++q) {
      int m = g4 * 4 + q;
      hchk[(size_t)(b0 + m) * 256 + j] = h[q];
    }
  } else {
#pragma unroll
    for (int q = 0; q < 4; ++q) hfin[g4 * 4 + q][j] = h[q];
    __syncthreads();
    // wave w reduces output row b0+w
    float s = 0.0f;
#pragma unroll
    for (int i = 0; i < 4; ++i) {
      int k = lane + 64 * i;
      s += hfin[w][k] * Wout[k];
    }
#pragma unroll
    for (int off = 32; off > 0; off >>= 1) s += __shfl_xor(s, off, 64);
    if (lane == 0) out[b0 + w] = sigm(s + bout[0]);
  }
}

extern "C" void kernel_launch(void* const* d_in, const int* in_sizes, int n_in,
                              void* d_out, int out_size, void* d_ws, size_t ws_size,
                              hipStream_t stream) {
  const float* x    = (const float*)d_in[0];
  const float* Wih  = (const float*)d_in[1];
  const float* Whh  = (const float*)d_in[2];
  const float* bih  = (const float*)d_in[3];
  const float* bhh  = (const float*)d_in[4];
  const float* Wout = (const float*)d_in[5];
  const float* bout = (const float*)d_in[6];
  float* out = (float*)d_out;

  const size_t HBYTES = (size_t)BB * HH * sizeof(float);                 // 256 KB h checkpoint
  const size_t STEP_BYTES = (size_t)BB * G3 * sizeof(unsigned short);    // 384 KB per timestep
  size_t gi_cap = ws_size > HBYTES ? ws_size - HBYTES : 0;
  long tc = (long)(gi_cap / STEP_BYTES);
  if (tc > TT) tc = TT;

  if (tc >= 32) {
    float* hchk = (float*)d_ws;
    unsigned short* gi = (unsigned short*)((char*)d_ws + HBYTES);
    for (int t0 = 0; t0 < TT; t0 += (int)tc) {
      int nt = (TT - t0) < (int)tc ? (TT - t0) : (int)tc;
      gi_gemm<<<dim3(512), dim3(1024), 0, stream>>>(
          x + (size_t)t0 * BB * II, Wih, gi, nt * 16);
      gru_step<false><<<dim3(16), dim3(1024), 0, stream>>>(
          x, Wih, Whh, bih, bhh, Wout, bout, gi, hchk, out, t0, nt);
    }
  } else {
    gru_step<true><<<dim3(16), dim3(1024), 0, stream>>>(
        x, Wih, Whh, bih, bhh, Wout, bout, nullptr, nullptr, out, 0, TT);
  }
}

// Round 2
// 1078.243 us; speedup vs baseline: 4.3889x; 4.3889x over previous
//
#include <hip/hip_runtime.h>
#include <hip/hip_bf16.h>

// GRU forward, T=512 B=256 I=H=256 fp32 in, fp32 [B,1] out.
// v2: fix the register-spill catastrophe of v1 (VGPR_Count=64 -> weights in
// scratch, 4497us). Key changes:
//  - gru_step2: 16 blocks x 512 thr, amdgpu_waves_per_eu(2,2) pins 2 waves/EU
//    -> VGPR cap 256. r,z gate weights resident in VGPRs (128/lane); n gate
//    weights resident in LDS (128KB, fragment-ordered, conflict-free
//    ds_read_b128). One barrier/step.
//  - exp-scaling folded into weights/biases at init: sigmoid = rcp(1+exp2(a')),
//    tanh = 1-2*rcp(1+exp2(y')) with a' = -log2e*a, y' = 2log2e*y. No runtime
//    scaling VALU; raw v_exp_f32/v_rcp_f32 via builtins.
//  - gi stored in fragment order: per (t,btile) 24KB block laid out
//    [g][w][lane][tl][q] so each gru lane loads 3x dwordx4/step, coalesced;
//    prefetched one step ahead. Biases (+scale) folded into gi at gi_gemm time.
//  - gi_gemm2: one gate per block (weight frags = 32 VGPRs only, can't spill),
//    waves_per_eu(4,4), double-buffered A staging, g = blockIdx.x%3 so the 3
//    gate-blocks of a tile-group are co-resident (x read once from HBM).

#define TT 512
#define BB 256
#define II 256
#define HH 256

#define SRZ (-1.4426950408889634f)   // -log2(e)
#define SN  (2.8853900817779268f)    // 2*log2(e)

typedef __attribute__((ext_vector_type(8))) short short8;
typedef __attribute__((ext_vector_type(4))) float f32x4;

__device__ __forceinline__ unsigned short rne_bf16(float f) {
  union { float f; unsigned u; } v; v.f = f;
  unsigned r = v.u + 0x7FFFu + ((v.u >> 16) & 1u);
  return (unsigned short)(r >> 16);
}
__device__ __forceinline__ float bf2f(unsigned short b) {
  union { unsigned u; float f; } v; v.u = ((unsigned)b) << 16;
  return v.f;
}
__device__ __forceinline__ float sigm(float x) { return 1.0f / (1.0f + __expf(-x)); }
__device__ __forceinline__ float tanhfast(float x) {
  return 1.0f - 2.0f / (__expf(2.0f * x) + 1.0f);
}

// 8 contiguous fp32 -> bf16 fragment
__device__ __forceinline__ short8 ldw8(const float* __restrict__ p) {
  float4 a = *reinterpret_cast<const float4*>(p);
  float4 b = *reinterpret_cast<const float4*>(p + 4);
  short8 r;
  r[0] = (short)rne_bf16(a.x); r[1] = (short)rne_bf16(a.y);
  r[2] = (short)rne_bf16(a.z); r[3] = (short)rne_bf16(a.w);
  r[4] = (short)rne_bf16(b.x); r[5] = (short)rne_bf16(b.y);
  r[6] = (short)rne_bf16(b.z); r[7] = (short)rne_bf16(b.w);
  return r;
}
// same, pre-scaled (fold exp2 conversion into resident weights at init)
__device__ __forceinline__ short8 ldw8s(const float* __restrict__ p, float s) {
  float4 a = *reinterpret_cast<const float4*>(p);
  float4 b = *reinterpret_cast<const float4*>(p + 4);
  short8 r;
  r[0] = (short)rne_bf16(a.x * s); r[1] = (short)rne_bf16(a.y * s);
  r[2] = (short)rne_bf16(a.z * s); r[3] = (short)rne_bf16(a.w * s);
  r[4] = (short)rne_bf16(b.x * s); r[5] = (short)rne_bf16(b.y * s);
  r[6] = (short)rne_bf16(b.z * s); r[7] = (short)rne_bf16(b.w * s);
  return r;
}

// swizzled [16][256] ushort LDS tile
#define SWZ(m, k) ((m) * 256 + ((k) ^ ((m) * 16)))

// cooperative stage: 16 rows x 256 fp32 -> swizzled bf16 LDS (1024 threads)
__device__ __forceinline__ void stage16(unsigned short* lds,
                                        const float* __restrict__ src, int tid) {
  int m = tid >> 6, k0 = (tid & 63) << 2;
  float4 v = *reinterpret_cast<const float4*>(src + m * 256 + k0);
  ushort4 b;
  b.x = rne_bf16(v.x); b.y = rne_bf16(v.y);
  b.z = rne_bf16(v.z); b.w = rne_bf16(v.w);
  *reinterpret_cast<ushort4*>(lds + SWZ(m, k0)) = b;
}

__device__ __forceinline__ short8 lda(const unsigned short* lds, int lane, int c) {
  int m = lane & 15;
  int k0 = c * 32 + (lane >> 4) * 8;
  return *reinterpret_cast<const short8*>(lds + SWZ(m, k0));
}

__device__ __forceinline__ f32x4 mfma16(short8 a, short8 b, f32x4 c) {
  return __builtin_amdgcn_mfma_f32_16x16x32_bf16(a, b, c, 0, 0, 0);
}

// ---------------- Phase 1: gi = (x @ W_ih^T + bias) * scale, frag-ordered ----
// gi layout per (t,btile): base = (t*16+btile)*12288 ushorts; within:
// [g][w][lane][tl][q] = g*4096 + w*512 + lane*8 + tl*4 + q.
__global__ __launch_bounds__(1024)
__attribute__((amdgpu_waves_per_eu(4, 4)))
void gi_gemm2(const float* __restrict__ x, const float* __restrict__ Wih,
              const float* __restrict__ bih, const float* __restrict__ bhh,
              unsigned short* __restrict__ gi, int ntiles) {
  __shared__ unsigned short ax[2][4096];
  int tid = threadIdx.x, l = tid & 63, wg = tid >> 6;
  int g4 = l >> 4, i15 = l & 15;
  int g = blockIdx.x % 3;          // gate; consecutive blocks share x tiles
  int tgrp = blockIdx.x / 3;
  int ngrp = gridDim.x / 3;
  int nb = 16 * wg + i15;          // output column within gate block
  float scale = (g == 2) ? SN : SRZ;
  float bias = (g == 2) ? bih[512 + nb] : (bih[g * 256 + nb] + bhh[g * 256 + nb]);
  short8 wf[8];
#pragma unroll
  for (int c = 0; c < 8; ++c)
    wf[c] = ldw8(Wih + (size_t)(g * 256 + nb) * 256 + c * 32 + g4 * 8);

  int tile = tgrp;
  if (tile >= ntiles) return;
  stage16(ax[0], x + (size_t)tile * 4096, tid);
  __syncthreads();
  int cur = 0;
  int slot = (nb >> 5) * 512 + (((g4 << 4) | i15)) * 8 + ((nb >> 4) & 1) * 4;
  while (true) {
    int nxt_tile = tile + ngrp;
    if (nxt_tile < ntiles) stage16(ax[cur ^ 1], x + (size_t)nxt_tile * 4096, tid);
    short8 a[8];
#pragma unroll
    for (int c = 0; c < 8; ++c) a[c] = lda(ax[cur], l, c);
    f32x4 acc = {0, 0, 0, 0};
#pragma unroll
    for (int c = 0; c < 8; ++c) acc = mfma16(a[c], wf[c], acc);
    ushort4 o;
    o.x = rne_bf16((acc[0] + bias) * scale);
    o.y = rne_bf16((acc[1] + bias) * scale);
    o.z = rne_bf16((acc[2] + bias) * scale);
    o.w = rne_bf16((acc[3] + bias) * scale);
    *reinterpret_cast<ushort4*>(&gi[(size_t)tile * 12288 + g * 4096 + slot]) = o;
    if (nxt_tile >= ntiles) break;
    __syncthreads();
    cur ^= 1;
    tile = nxt_tile;
  }
}

// ---------------- Phase 2: persistent GRU recurrence (v2) ----------------
__global__ __launch_bounds__(512)
__attribute__((amdgpu_waves_per_eu(2, 2)))
void gru_step2(const float* __restrict__ Whh, const float* __restrict__ bhh,
               const float* __restrict__ Wout, const float* __restrict__ bout,
               const unsigned short* __restrict__ gi, float* __restrict__ hchk,
               float* __restrict__ out, int t0, int nt) {
  __shared__ __align__(16) unsigned char arena[147456];  // 144 KB
  unsigned short* ldsn = (unsigned short*)arena;                    // 128KB n-gate frags
  unsigned short* hbuf0 = (unsigned short*)(arena + 131072);        // 8KB
  unsigned short* hbuf1 = (unsigned short*)(arena + 139264);        // 8KB

  int tid = threadIdx.x, l = tid & 63, w = tid >> 6;
  int g4 = l >> 4, i15 = l & 15;
  int bx = blockIdx.x, b0 = bx * 16;

  // resident weights: r,z gates pre-scaled by -log2e; n gate (scaled 2log2e) to LDS
  short8 wr[2][8], wz[2][8];
  float cn[2];
#pragma unroll
  for (int tl = 0; tl < 2; ++tl) {
    int j = 32 * w + 16 * tl + i15;
#pragma unroll
    for (int c = 0; c < 8; ++c) {
      int ko = c * 32 + g4 * 8;
      wr[tl][c] = ldw8s(Whh + (size_t)j * 256 + ko, SRZ);
      wz[tl][c] = ldw8s(Whh + (size_t)(256 + j) * 256 + ko, SRZ);
      short8 fn = ldw8s(Whh + (size_t)(512 + j) * 256 + ko, SN);
      *reinterpret_cast<short8*>(&ldsn[(size_t)(((w * 2 + tl) * 8 + c) * 64 + l) * 8]) = fn;
    }
    cn[tl] = SN * bhh[512 + j];
  }

  f32x4 h[2] = {{0, 0, 0, 0}, {0, 0, 0, 0}};  // h[tl][q], fp32
  if (t0 == 0) {
    for (int idx = tid; idx < 4096; idx += 512) hbuf0[idx] = 0;
  } else {
#pragma unroll
    for (int tl = 0; tl < 2; ++tl) {
      int j = 32 * w + 16 * tl + i15;
#pragma unroll
      for (int q = 0; q < 4; ++q) {
        float hv = hchk[(size_t)(b0 + 4 * g4 + q) * 256 + j];
        h[tl][q] = hv;
        hbuf0[SWZ(4 * g4 + q, j)] = rne_bf16(hv);
      }
    }
  }
  __syncthreads();

  // gi prefetch: 3 coalesced dwordx4 per lane per step
  int lslot = w * 512 + l * 8;
  short8 gc[3], gn_[3];
  {
    const unsigned short* p = gi + (size_t)bx * 12288 + lslot;
    gc[0] = *reinterpret_cast<const short8*>(p);
    gc[1] = *reinterpret_cast<const short8*>(p + 4096);
    gc[2] = *reinterpret_cast<const short8*>(p + 8192);
  }

  // per-lane base for n-gate frag reads (imm offsets per (tl,c))
  const unsigned short* nbase = ldsn + (size_t)l * 8 + (size_t)(w * 2) * 8 * 64 * 8;

  for (int lt = 0; lt < nt; ++lt) {
    if (lt + 1 < nt) {
      const unsigned short* p = gi + ((size_t)(lt + 1) * 16 + bx) * 12288 + lslot;
      gn_[0] = *reinterpret_cast<const short8*>(p);
      gn_[1] = *reinterpret_cast<const short8*>(p + 4096);
      gn_[2] = *reinterpret_cast<const short8*>(p + 8192);
    }
    const unsigned short* hb = (lt & 1) ? hbuf1 : hbuf0;
    unsigned short* hw = (lt & 1) ? hbuf0 : hbuf1;

    f32x4 ar[2] = {{0, 0, 0, 0}, {0, 0, 0, 0}};
    f32x4 az[2] = {{0, 0, 0, 0}, {0, 0, 0, 0}};
    f32x4 an[2] = {{0, 0, 0, 0}, {0, 0, 0, 0}};
#pragma unroll
    for (int half = 0; half < 2; ++half) {
      short8 ah[4];
#pragma unroll
      for (int cc = 0; cc < 4; ++cc) ah[cc] = lda(hb, l, half * 4 + cc);
#pragma unroll
      for (int cc = 0; cc < 4; ++cc) {
        int c = half * 4 + cc;
#pragma unroll
        for (int tl = 0; tl < 2; ++tl) {
          short8 fn = *reinterpret_cast<const short8*>(nbase + (tl * 8 + c) * 512);
          ar[tl] = mfma16(ah[cc], wr[tl][c], ar[tl]);
          az[tl] = mfma16(ah[cc], wz[tl][c], az[tl]);
          an[tl] = mfma16(ah[cc], fn, an[tl]);
        }
      }
    }
#pragma unroll
    for (int tl = 0; tl < 2; ++tl) {
#pragma unroll
      for (int q = 0; q < 4; ++q) {
        float gr = bf2f((unsigned short)gc[0][tl * 4 + q]);
        float gz = bf2f((unsigned short)gc[1][tl * 4 + q]);
        float gv = bf2f((unsigned short)gc[2][tl * 4 + q]);
        // r = sigmoid(true a_r): a' = -log2e*a already (weights+gi pre-scaled)
        float r = __builtin_amdgcn_rcpf(1.0f + __builtin_amdgcn_exp2f(ar[tl][q] + gr));
        float zz = __builtin_amdgcn_rcpf(1.0f + __builtin_amdgcn_exp2f(az[tl][q] + gz));
        float y = gv + r * (an[tl][q] + cn[tl]);  // = 2log2e * n-preact
        float nn = 1.0f - 2.0f * __builtin_amdgcn_rcpf(1.0f + __builtin_amdgcn_exp2f(y));
        float hq = nn + zz * (h[tl][q] - nn);
        h[tl][q] = hq;
        hw[SWZ(4 * g4 + q, 32 * w + 16 * tl + i15)] = rne_bf16(hq);
      }
    }
    gc[0] = gn_[0]; gc[1] = gn_[1]; gc[2] = gn_[2];
    __syncthreads();
  }

  if (t0 + nt < TT) {
#pragma unroll
    for (int tl = 0; tl < 2; ++tl) {
      int j = 32 * w + 16 * tl + i15;
#pragma unroll
      for (int q = 0; q < 4; ++q)
        hchk[(size_t)(b0 + 4 * g4 + q) * 256 + j] = h[tl][q];
    }
  } else {
    // overlay hfin on ldsn (weights dead; last loop barrier protects reads)
    float* hfin = (float*)arena;
#pragma unroll
    for (int tl = 0; tl < 2; ++tl) {
      int j = 32 * w + 16 * tl + i15;
#pragma unroll
      for (int q = 0; q < 4; ++q) hfin[(4 * g4 + q) * 256 + j] = h[tl][q];
    }
    __syncthreads();
#pragma unroll
    for (int rr = 0; rr < 2; ++rr) {
      int r = 2 * w + rr;
      float s = 0.0f;
#pragma unroll
      for (int i = 0; i < 4; ++i) {
        int k = l + 64 * i;
        s += hfin[r * 256 + k] * Wout[k];
      }
#pragma unroll
      for (int off = 32; off > 0; off >>= 1) s += __shfl_xor(s, off, 64);
      if (l == 0) out[b0 + r] = sigm(s + bout[0]);
    }
  }
}

// ---------------- Legacy fused fallback (v1, used only if ws too small) ------
__global__ __launch_bounds__(1024, 1) void gru_fused_legacy(
    const float* __restrict__ x, const float* __restrict__ Wih,
    const float* __restrict__ Whh, const float* __restrict__ bih,
    const float* __restrict__ bhh, const float* __restrict__ Wout,
    const float* __restrict__ bout, float* __restrict__ out) {
  __shared__ unsigned short hbuf[2][16 * 256];
  __shared__ unsigned short xbuf[2][16 * 256];
  __shared__ float hfin[16][256];
  int tid = threadIdx.x, lane = tid & 63, w = tid >> 6;
  int i15 = lane & 15, g4 = lane >> 4;
  int b0 = blockIdx.x * 16;
  int j = 16 * w + i15;

  short8 whh0[8], whh1[8], whh2[8], wih0[8], wih1[8], wih2[8];
#pragma unroll
  for (int c = 0; c < 8; ++c) {
    int ko = c * 32 + g4 * 8;
    whh0[c] = ldw8(Whh + (size_t)j * 256 + ko);
    whh1[c] = ldw8(Whh + (size_t)(256 + j) * 256 + ko);
    whh2[c] = ldw8(Whh + (size_t)(512 + j) * 256 + ko);
    wih0[c] = ldw8(Wih + (size_t)j * 256 + ko);
    wih1[c] = ldw8(Wih + (size_t)(256 + j) * 256 + ko);
    wih2[c] = ldw8(Wih + (size_t)(512 + j) * 256 + ko);
  }
  float bias_r = bih[j] + bhh[j];
  float bias_z = bih[256 + j] + bhh[256 + j];
  float bihn = bih[512 + j], bhhn = bhh[512 + j];

  f32x4 h = {0, 0, 0, 0};
  for (int idx = tid; idx < 16 * 256; idx += 1024) hbuf[0][idx] = 0;
  stage16(xbuf[0], x + (size_t)b0 * II, tid);
  __syncthreads();

  for (int lt = 0; lt < TT; ++lt) {
    int cur = lt & 1, nxt = cur ^ 1;
    short8 ah[8], axf[8];
#pragma unroll
    for (int c = 0; c < 8; ++c) ah[c] = lda(hbuf[cur], lane, c);
#pragma unroll
    for (int c = 0; c < 8; ++c) axf[c] = lda(xbuf[cur], lane, c);
    f32x4 gr = {0, 0, 0, 0}, gz = {0, 0, 0, 0}, gn = {0, 0, 0, 0};
    f32x4 ar = {0, 0, 0, 0}, az = {0, 0, 0, 0}, an = {0, 0, 0, 0};
#pragma unroll
    for (int c = 0; c < 8; ++c) {
      gr = mfma16(axf[c], wih0[c], gr);
      gz = mfma16(axf[c], wih1[c], gz);
      gn = mfma16(axf[c], wih2[c], gn);
    }
    if (lt + 1 < TT)
      stage16(xbuf[nxt], x + ((size_t)(lt + 1) * BB + b0) * II, tid);
#pragma unroll
    for (int c = 0; c < 8; ++c) {
      ar = mfma16(ah[c], whh0[c], ar);
      az = mfma16(ah[c], whh1[c], az);
      an = mfma16(ah[c], whh2[c], an);
    }
#pragma unroll
    for (int q = 0; q < 4; ++q) {
      float r = sigm(ar[q] + gr[q] + bias_r);
      float zz = sigm(az[q] + gz[q] + bias_z);
      float nn = tanhfast(gn[q] + bihn + r * (an[q] + bhhn));
      float hq = (1.0f - zz) * nn + zz * h[q];
      h[q] = hq;
      hbuf[nxt][SWZ(g4 * 4 + q, j)] = rne_bf16(hq);
    }
    __syncthreads();
  }
#pragma unroll
  for (int q = 0; q < 4; ++q) hfin[g4 * 4 + q][j] = h[q];
  __syncthreads();
  float s = 0.0f;
#pragma unroll
  for (int i = 0; i < 4; ++i) {
    int k = lane + 64 * i;
    s += hfin[w][k] * Wout[k];
  }
#pragma unroll
  for (int off = 32; off > 0; off >>= 1) s += __shfl_xor(s, off, 64);
  if (lane == 0) out[b0 + w] = sigm(s + bout[0]);
}

extern "C" void kernel_launch(void* const* d_in, const int* in_sizes, int n_in,
                              void* d_out, int out_size, void* d_ws, size_t ws_size,
                              hipStream_t stream) {
  const float* x    = (const float*)d_in[0];
  const float* Wih  = (const float*)d_in[1];
  const float* Whh  = (const float*)d_in[2];
  const float* bih  = (const float*)d_in[3];
  const float* bhh  = (const float*)d_in[4];
  const float* Wout = (const float*)d_in[5];
  const float* bout = (const float*)d_in[6];
  float* out = (float*)d_out;

  const size_t HBYTES = (size_t)BB * HH * sizeof(float);               // 256 KB
  const size_t STEP_BYTES = (size_t)16 * 12288 * sizeof(unsigned short);  // 384 KB / t
  size_t gi_cap = ws_size > HBYTES ? ws_size - HBYTES : 0;
  long tc = (long)(gi_cap / STEP_BYTES);
  if (tc > TT) tc = TT;

  if (tc >= 32) {
    float* hchk = (float*)d_ws;
    unsigned short* gi = (unsigned short*)((char*)d_ws + HBYTES);
    for (int t0 = 0; t0 < TT; t0 += (int)tc) {
      int nt = (TT - t0) < (int)tc ? (TT - t0) : (int)tc;
      gi_gemm2<<<dim3(3 * 1024), dim3(1024), 0, stream>>>(
          x + (size_t)t0 * BB * II, Wih, bih, bhh, gi, nt * 16);
      gru_step2<<<dim3(16), dim3(512), 0, stream>>>(
          Whh, bhh, Wout, bout, gi, hchk, out, t0, nt);
    }
  } else {
    gru_fused_legacy<<<dim3(16), dim3(1024), 0, stream>>>(
        x, Wih, Whh, bih, bhh, Wout, bout, out);
  }
}